// Round 5
// baseline (158.333 us; speedup 1.0000x reference)
//
#include <hip/hip_runtime.h>
#include <math.h>

// S4D kernel materialization — R5 = MEASUREMENT ROUND.
// Identical compute structure to R4 (2nd-order real recurrence, 4 waves/block,
// 16 n/wave, lane owns l = lane + 64*j), but the whole compute+epilogue is
// repeated REP=8 times inside the kernel. A runtime zero (rz, loaded from LDS
// so the compiler can't constant-fold) is fma'd into the exp/sin arguments
// with the repeat index, making repeats formally distinct (no CSE) while
// numerically identical -> output stays correct on every repeat.
// Purpose: (a) kernel dur ~ 8*k4 makes it appear in rocprof top-5 with full
// counters (VALUBusy / Occupancy / conflicts); (b) total = O + 8*k4 combined
// with R4's total = O + k4 pins down the true kernel time k4 = (dur5-dur4)/7,
// resolving the O=56-vs-70 harness-overhead ambiguity.

#define HH 1024
#define NN 64
#define TPB 256
#define NWAVE 4
#define NPW 16         // n per wave
#define STEP 64        // lanes per wave = l-stride per recurrence step
#define LPT 32         // 2048 / 64
#define RJ 33          // padded j-stride in reduce buffer
#define REP 8
#define LOG2E  1.4426950408889634f
#define INV2PI 0.15915494309189535f

__global__ __launch_bounds__(TPB, 4) void s4d_recur3_x8_kernel(
    const float* __restrict__ A_real,
    const float* __restrict__ A_imag,
    const float* __restrict__ B,
    const float* __restrict__ C,
    const float* __restrict__ inv_dt,
    float* __restrict__ out,
    int L)
{
    __shared__ float4 pA[NN];              // (dre*log2e, dim/2pi, 2*Cm.re, 2*Cm.im)
    __shared__ float4 pW[NN];              // (Wr, Wi, 2*Wr, |W|^2)
    __shared__ float red[NWAVE * STEP * RJ];  // partials, ~33.8 KB
    __shared__ float rzero;                // runtime 0.0f, opaque to compiler

    const int h    = blockIdx.x;
    const int t    = threadIdx.x;
    const int lane = t & 63;
    const int w    = t >> 6;

    if (t == 0) rzero = 0.0f * inv_dt[0];  // = 0.0f at runtime
    if (t < NN) {
        const int n  = t;
        const int hn = h * NN + n;
        float Ar = A_real[hn];
        float Ai = A_imag[hn];
        float dt = expf(inv_dt[h]);          // rate = 1.0
        float are = -expf(Ar);               // Re(A) = -exp(A_real)
        float dre = dt * are;                // Re(dtA)  (<= 0)
        float dim = dt * Ai;                 // Im(dtA)
        float er = expf(dre);
        float s, c;
        sincosf(dim, &s, &c);
        float em1r = er * c - 1.0f;
        float em1i = er * s;
        float inv = 1.0f / (are * are + Ai * Ai);
        float zr = (em1r * are + em1i * Ai) * inv;
        float zi = (em1i * are - em1r * Ai) * inv;
        float br = B[2 * hn],  bi = B[2 * hn + 1];
        float Cr = C[2 * hn],  Ci = C[2 * hn + 1];
        float bcr = br * Cr - bi * Ci;
        float bci = br * Ci + bi * Cr;
        float cmr = bcr * zr - bci * zi;
        float cmi = bcr * zi + bci * zr;

        float dreL = dre * LOG2E;
        float dimR = dim * INV2PI;
        float we = exp2f(dreL * (float)STEP);
        float wx = dimR * (float)STEP;
        float wf = wx - floorf(wx);
        float Wc = __builtin_amdgcn_cosf(wf);
        float Ws = __builtin_amdgcn_sinf(wf);
        float Wr = we * Wc, Wi = we * Ws;
        pA[n] = make_float4(dreL, dimR, 2.0f * cmr, 2.0f * cmi);
        pW[n] = make_float4(Wr, Wi, 2.0f * Wr, Wr * Wr + Wi * Wi);
    }
    __syncthreads();

    const float rz = rzero;            // runtime 0, defeats cross-repeat CSE
    const float tf = (float)lane;
    const int n0 = w * NPW;

    for (int r = 0; r < REP; ++r) {
        const float rf = (float)r;

        float acc[LPT];
#pragma unroll
        for (int j = 0; j < LPT; ++j) acc[j] = 0.0f;

        for (int g = 0; g < NPW; g += 4) {
            float xp[4], xc[4], aa[4], bb[4];
#pragma unroll
            for (int k = 0; k < 4; ++k) {
                const float4 p = pA[n0 + g + k];   // wave-uniform -> broadcast
                const float4 ww = pW[n0 + g + k];
                // z0 = 2*Cm * exp(dtA * lane); rz*rf == 0, repeat-dependent
                float e = __builtin_amdgcn_exp2f(fmaf(rz, rf, p.x * tf));
                float x = fmaf(rz, rf, p.y * tf);
                float f = x - floorf(x);
                float c = __builtin_amdgcn_cosf(f);
                float s = __builtin_amdgcn_sinf(f);
                float er = e * c, ei = e * s;
                float sr = p.z * er - p.w * ei;   // x0 = Re(z0)
                float si = p.z * ei + p.w * er;
                xp[k] = sr;
                xc[k] = sr * ww.x - si * ww.y;    // x1 = Re(z0 * W)
                aa[k] = ww.z;                     // 2*Re(W)
                bb[k] = ww.w;                     // |W|^2
            }
            acc[0] += (xp[0] + xp[1]) + (xp[2] + xp[3]);
#pragma unroll
            for (int j = 1; j < LPT; ++j) {
#pragma unroll
                for (int k = 0; k < 4; ++k) {
                    acc[j] += xc[k];
                    float xn = fmaf(aa[k], xc[k], -bb[k] * xp[k]);
                    xp[k] = xc[k];
                    xc[k] = xn;
                }
            }
        }

        // stash wave partials; lane stride RJ=33 floats (<=2-way alias, free)
        {
            float* dst = &red[(w * STEP + lane) * RJ];
#pragma unroll
            for (int j = 0; j < LPT; ++j) dst[j] = acc[j];
        }
        __syncthreads();

        // sum the 4 wave-partials; 8 outputs per thread, coalesced stores
#pragma unroll
        for (int q = 0; q < 8; ++q) {
            int p = t + TPB * q;          // 0..2047
            int j  = p >> 6;
            int l2 = p & 63;
            float sum = 0.0f;
#pragma unroll
            for (int v = 0; v < NWAVE; ++v)
                sum += red[(v * STEP + l2) * RJ + j];
            out[h * L + p] = sum;
        }
        __syncthreads();   // red[] reused next repeat
    }
}

extern "C" void kernel_launch(void* const* d_in, const int* in_sizes, int n_in,
                              void* d_out, int out_size, void* d_ws, size_t ws_size,
                              hipStream_t stream) {
    const float* A_real = (const float*)d_in[0];
    const float* A_imag = (const float*)d_in[1];
    const float* B      = (const float*)d_in[2];
    const float* C      = (const float*)d_in[3];
    const float* inv_dt = (const float*)d_in[4];
    int L = out_size / HH;   // 2048

    s4d_recur3_x8_kernel<<<HH, TPB, 0, stream>>>(A_real, A_imag, B, C, inv_dt,
                                                 (float*)d_out, L);
}

// Round 6
// 76.023 us; speedup vs baseline: 2.0827x; 2.0827x over previous
//
#include <hip/hip_runtime.h>
#include <math.h>

// S4D kernel materialization:
//   dt = exp(inv_dt[h]);  A = -exp(A_real) + i*A_imag;  dtA = dt*A
//   Cm = (B*C) * (exp(dtA)-1)/A          (complex, per h,n)
//   K[h,l] = 2 * Re( sum_n Cm[h,n] * exp(dtA[h,n] * l) )
//
// H=1024, N=64, CH=1, L=2048. Output (1,H,L) float32 = 8 MB.
//
// R6: packed fp32. R5 measurement: kernel ~13.9 us/rep, VALUBusy 81%,
// effective clock ~1.5 GHz under dense fp32 (m07: 103 TF full-chip = 65% of
// 2.4GHz spec). VALU-issue bound -> cut instructions with VOP3P packed fp32:
// pair the n recurrence chains into float2 registers; inner step =
// v_pk_mul + v_pk_fma + v_pk_add per TWO elements (1.5 instr/elem vs 3).
// Structure otherwise = R4: one h per block, 4 waves x 16 n, lane owns
// l = lane + 64*j (j=0..31), 2nd-order real recurrence
// x_{j+1} = 2Re(W) x_j - |W|^2 x_{j-1}, W = exp(dtA*64).

#define HH 1024
#define NN 64
#define TPB 256
#define NWAVE 4
#define NPW 16         // n per wave
#define STEP 64        // lanes per wave = l-stride per recurrence step
#define LPT 32         // 2048 / 64
#define RJ 33          // padded j-stride in reduce buffer
#define LOG2E  1.4426950408889634f
#define INV2PI 0.15915494309189535f

typedef float v2f __attribute__((ext_vector_type(2)));

__global__ __launch_bounds__(TPB, 4) void s4d_pk_kernel(
    const float* __restrict__ A_real,
    const float* __restrict__ A_imag,
    const float* __restrict__ B,
    const float* __restrict__ C,
    const float* __restrict__ inv_dt,
    float* __restrict__ out,
    int L)
{
    __shared__ float4 pA[NN];              // (dre*log2e, dim/2pi, 2*Cm.re, 2*Cm.im)
    __shared__ float4 pW[NN];              // (Wr, Wi, 2*Wr, -|W|^2)
    __shared__ float red[NWAVE * STEP * RJ];  // partials, ~33.8 KB

    const int h    = blockIdx.x;
    const int t    = threadIdx.x;
    const int lane = t & 63;
    const int w    = t >> 6;

    if (t < NN) {
        const int n  = t;
        const int hn = h * NN + n;
        float Ar = A_real[hn];
        float Ai = A_imag[hn];
        float dt = expf(inv_dt[h]);          // rate = 1.0
        float are = -expf(Ar);               // Re(A) = -exp(A_real)
        float dre = dt * are;                // Re(dtA)  (<= 0)
        float dim = dt * Ai;                 // Im(dtA)
        // exp(dtA) - 1
        float er = expf(dre);
        float s, c;
        sincosf(dim, &s, &c);
        float em1r = er * c - 1.0f;
        float em1i = er * s;
        // (exp(dtA)-1)/A  via conj(A)/|A|^2
        float inv = 1.0f / (are * are + Ai * Ai);
        float zr = (em1r * are + em1i * Ai) * inv;
        float zi = (em1i * are - em1r * Ai) * inv;
        // Bc * Cc
        float br = B[2 * hn],  bi = B[2 * hn + 1];
        float Cr = C[2 * hn],  Ci = C[2 * hn + 1];
        float bcr = br * Cr - bi * Ci;
        float bci = br * Ci + bi * Cr;
        // Cm = (Bc*Cc) * z, fold in the final 2x
        float cmr = bcr * zr - bci * zi;
        float cmi = bcr * zi + bci * zr;

        float dreL = dre * LOG2E;
        float dimR = dim * INV2PI;
        // W = exp(dtA * STEP)
        float we = exp2f(dreL * (float)STEP);
        float wx = dimR * (float)STEP;
        float wf = wx - floorf(wx);
        float Wc = __builtin_amdgcn_cosf(wf);
        float Ws = __builtin_amdgcn_sinf(wf);
        float Wr = we * Wc, Wi = we * Ws;
        pA[n] = make_float4(dreL, dimR, 2.0f * cmr, 2.0f * cmi);
        pW[n] = make_float4(Wr, Wi, 2.0f * Wr, -(Wr * Wr + Wi * Wi));
    }
    __syncthreads();

    v2f acc2[LPT];
#pragma unroll
    for (int j = 0; j < LPT; ++j) acc2[j] = (v2f){0.0f, 0.0f};

    const float tf = (float)lane;
    const int n0 = w * NPW;

    for (int g = 0; g < NPW; g += 4) {
        // scalar startup for 4 chains (3 trans each), then pack into 2 pairs
        float x0s[4], x1s[4], aas[4], nbs[4];
#pragma unroll
        for (int k = 0; k < 4; ++k) {
            const float4 p  = pA[n0 + g + k];   // wave-uniform -> LDS broadcast
            const float4 ww = pW[n0 + g + k];
            // z0 = 2*Cm * exp(dtA * lane)
            float e = __builtin_amdgcn_exp2f(p.x * tf);
            float f = __builtin_amdgcn_fractf(p.y * tf);
            float c = __builtin_amdgcn_cosf(f);
            float s = __builtin_amdgcn_sinf(f);
            float er = e * c, ei = e * s;
            float sr = p.z * er - p.w * ei;     // x0 = Re(z0)
            float si = p.z * ei + p.w * er;
            x0s[k] = sr;
            x1s[k] = sr * ww.x - si * ww.y;     // x1 = Re(z0 * W)
            aas[k] = ww.z;                      // 2*Re(W)
            nbs[k] = ww.w;                      // -|W|^2
        }
        v2f xp0 = (v2f){x0s[0], x0s[1]}, xc0 = (v2f){x1s[0], x1s[1]};
        v2f xp1 = (v2f){x0s[2], x0s[3]}, xc1 = (v2f){x1s[2], x1s[3]};
        const v2f aa0 = (v2f){aas[0], aas[1]}, nb0 = (v2f){nbs[0], nbs[1]};
        const v2f aa1 = (v2f){aas[2], aas[3]}, nb1 = (v2f){nbs[2], nbs[3]};

        acc2[0] += xp0 + xp1;                   // j = 0 contribution
#pragma unroll
        for (int j = 1; j < LPT; ++j) {
            acc2[j] += xc0;                     // v_pk_add_f32
            acc2[j] += xc1;
            v2f t0 = nb0 * xp0;                 // v_pk_mul_f32
            v2f t1 = nb1 * xp1;
            v2f n0v = __builtin_elementwise_fma(aa0, xc0, t0);  // v_pk_fma_f32
            v2f n1v = __builtin_elementwise_fma(aa1, xc1, t1);
            xp0 = xc0; xc0 = n0v;
            xp1 = xc1; xc1 = n1v;
        }
    }

    // stash this wave's 32 partials (horizontal add of the chain pair here);
    // lane stride RJ=33 floats keeps bank aliasing <=2-way (free)
    {
        float* dst = &red[(w * STEP + lane) * RJ];
#pragma unroll
        for (int j = 0; j < LPT; ++j) dst[j] = acc2[j].x + acc2[j].y;
    }
    __syncthreads();

    // sum the 4 wave-partials; 8 outputs per thread, coalesced stores
#pragma unroll
    for (int q = 0; q < 8; ++q) {
        int p  = t + TPB * q;          // 0..2047
        int j  = p >> 6;
        int l2 = p & 63;
        float sum = 0.0f;
#pragma unroll
        for (int v = 0; v < NWAVE; ++v)
            sum += red[(v * STEP + l2) * RJ + j];
        out[h * L + p] = sum;
    }
}

extern "C" void kernel_launch(void* const* d_in, const int* in_sizes, int n_in,
                              void* d_out, int out_size, void* d_ws, size_t ws_size,
                              hipStream_t stream) {
    const float* A_real = (const float*)d_in[0];
    const float* A_imag = (const float*)d_in[1];
    const float* B      = (const float*)d_in[2];
    const float* C      = (const float*)d_in[3];
    const float* inv_dt = (const float*)d_in[4];
    int L = out_size / HH;   // 2048

    s4d_pk_kernel<<<HH, TPB, 0, stream>>>(A_real, A_imag, B, C, inv_dt,
                                          (float*)d_out, L);
}